// Round 4
// baseline (50.177 us; speedup 1.0000x reference)
//
#include <hip/hip_runtime.h>
#include <hip/hip_bf16.h>

#define NN 512
#define FIN 128
#define HH 4
#define DD 64
#define SW 68   // permuted/padded e-width: 17 groups x 4

// ws layout (floats):
//  h_ws   [8][512][64]        262144  @ 0
//  azi_ws [8][512][68]        278528  @ 262144   (|a|-scaled, e-permuted, bias-folded)
//  azj_ws [8][512][68]        278528  @ 540672
//  adi_ws [8][512]            4096    @ 819200   (0.6 * sum_e a*zi')
//  adj_ws [8][512]            4096    @ 823296
//  pacc   [8][8][512][64]     2097152 @ 827392
//  pm     [8][4096]           32768   @ 2924544
//  ps     [8][4096]           32768   @ 2957312
//  sgn_ws [4][17]             68      @ 2990080  (+-0.4 per group)
//  pa_ws  [4][68]             272     @ 2990148  (|a| at permuted slot, 0=pad)
//  src_ws [4][68] (int)       272     @ 2990420  (source e per slot)

// ---------------------------------------------------------------------------
// prep: per-head sign partition of a. 1 block, 64 threads (4 active).
// ---------------------------------------------------------------------------
__global__ void prep_kernel(const float* __restrict__ a, float* __restrict__ sgn,
                            float* __restrict__ pa, int* __restrict__ src)
{
    int h = threadIdx.x;
    if (h >= HH) return;
    const float* ah = a + h * DD;
    int np = 0;
    for (int e = 0; e < DD; ++e) if (ah[e] >= 0.f) ++np;
    int GP = (np + 3) >> 2;                  // positive groups
    for (int s = 0; s < SW; ++s) { src[h*SW+s] = 0; pa[h*SW+s] = 0.f; }
    int ip = 0, in_ = 4 * GP;
    for (int e = 0; e < DD; ++e) {
        float v = ah[e];
        int s = (v >= 0.f) ? (ip++) : (in_++);
        src[h*SW+s] = e; pa[h*SW+s] = fabsf(v);
    }
    for (int g = 0; g < 17; ++g) sgn[h*17+g] = (g < GP) ? 0.4f : -0.4f;
}

// ---------------------------------------------------------------------------
// proj: h = x@Wp + bp ; zi' = h@W1^T + Wcb ; zj = h@W2^T ;
// adi/adj signed dots ; permuted |a|-scaled azi/azj. 512 blocks x 256.
// ---------------------------------------------------------------------------
__global__ __launch_bounds__(256) void proj_kernel(
    const float* __restrict__ x, const float* __restrict__ Wp,
    const float* __restrict__ bp, const float* __restrict__ Wc,
    const float* __restrict__ Wcb, const float* __restrict__ a,
    const float* __restrict__ pa_ws, const int* __restrict__ src_ws,
    float* __restrict__ h_ws, float* __restrict__ azi_ws, float* __restrict__ azj_ws,
    float* __restrict__ adi_ws, float* __restrict__ adj_ws)
{
    int blk = blockIdx.x;
    int bh = blk >> 6;
    int n0 = (blk & 63) << 3;
    int b = bh >> 2, hh = bh & 3;

    __shared__ float xs[8 * FIN];
    __shared__ float hs[8][DD];
    __shared__ float Wcs[DD][2 * DD + 1];
    __shared__ float tzi[8][DD];
    __shared__ float tzj[8][DD];

    int t = threadIdx.x;

    ((float4*)xs)[t] = ((const float4*)(x + ((size_t)b * NN + n0) * FIN))[t];
    {
        const float4* wg = (const float4*)(Wc + (size_t)hh * DD * 2 * DD);
        #pragma unroll
        for (int k = 0; k < 8; ++k) {
            int idx = t + 256 * k;
            int r = idx >> 5, c4 = (idx & 31) * 4;
            float4 v = wg[idx];
            Wcs[r][c4] = v.x; Wcs[r][c4 + 1] = v.y;
            Wcs[r][c4 + 2] = v.z; Wcs[r][c4 + 3] = v.w;
        }
    }
    __syncthreads();

    int d = t & 63, w = t >> 6;            // rows w, w+4
    const float* Wph = Wp + (size_t)hh * FIN * DD;
    float bpv = bp[hh * DD + d];
    float acc0 = bpv, acc1 = bpv;
    #pragma unroll 8
    for (int i = 0; i < FIN; ++i) {
        float wv = Wph[i * DD + d];
        acc0 = fmaf(xs[w * FIN + i], wv, acc0);
        acc1 = fmaf(xs[(w + 4) * FIN + i], wv, acc1);
    }
    hs[w][d] = acc0; hs[w + 4][d] = acc1;
    float* hg = h_ws + ((size_t)bh * NN + n0) * DD;
    hg[w * DD + d] = acc0; hg[(w + 4) * DD + d] = acc1;
    __syncthreads();

    int e = d;
    float zb = Wcb[hh * DD + e];
    float zi0 = zb, zi1 = zb, zj0 = 0.f, zj1 = 0.f;
    #pragma unroll 8
    for (int d2 = 0; d2 < DD; ++d2) {
        float w1 = Wcs[e][d2];
        float w2 = Wcs[e][DD + d2];
        float h0 = hs[w][d2], h1 = hs[w + 4][d2];
        zi0 = fmaf(h0, w1, zi0); zi1 = fmaf(h1, w1, zi1);
        zj0 = fmaf(h0, w2, zj0); zj1 = fmaf(h1, w2, zj1);
    }
    tzi[w][e] = zi0; tzi[w + 4][e] = zi1;
    tzj[w][e] = zj0; tzj[w + 4][e] = zj1;

    // adi = 0.6*sum_e a*zi' ; adj = 0.6*sum_e a*zj  (signed a, unpermuted)
    float av = a[hh * DD + e];
    float p0 = av * zi0, p1 = av * zi1, q0 = av * zj0, q1 = av * zj1;
    #pragma unroll
    for (int off = 32; off; off >>= 1) {
        p0 += __shfl_xor(p0, off); p1 += __shfl_xor(p1, off);
        q0 += __shfl_xor(q0, off); q1 += __shfl_xor(q1, off);
    }
    if (e == 0) {
        adi_ws[bh * NN + n0 + w]     = 0.6f * p0;
        adi_ws[bh * NN + n0 + w + 4] = 0.6f * p1;
        adj_ws[bh * NN + n0 + w]     = 0.6f * q0;
        adj_ws[bh * NN + n0 + w + 4] = 0.6f * q1;
    }
    __syncthreads();

    // permuted |a|-scaled writes: 8 rows x 68 slots
    {
        int r = t >> 5, sl = t & 31;
        const int*   sh = src_ws + hh * SW;
        const float* ph = pa_ws + hh * SW;
        float* azib = azi_ws + ((size_t)bh * NN + n0) * SW;
        float* azjb = azj_ws + ((size_t)bh * NN + n0) * SW;
        for (int s = sl; s < SW; s += 32) {
            int se = sh[s]; float pav = ph[s];
            azib[(size_t)r * SW + s] = pav * tzi[r][se];
            azjb[(size_t)r * SW + s] = pav * tzj[r][se];
        }
    }
}

// ---------------------------------------------------------------------------
// attn partial: e-tile [64 i][64 j] per block, 4 waves x 16 i.
// grid = 8bh x 8it x 8js = 512 blocks x 256 thr. ONE barrier.
// ---------------------------------------------------------------------------
__global__ __launch_bounds__(256) void attn_kernel(
    const float* __restrict__ h_ws, const float* __restrict__ azi_ws,
    const float* __restrict__ azj_ws, const float* __restrict__ adi_ws,
    const float* __restrict__ adj_ws, const float* __restrict__ sgn_ws,
    float* __restrict__ pacc, float* __restrict__ pm, float* __restrict__ ps)
{
    int blk = blockIdx.x;
    int js = blk & 7, it = (blk >> 3) & 7, bh = blk >> 6;
    int j0 = js << 6, i0 = it << 6, hh = bh & 3;

    __shared__ float azis[64 * SW];    // 17.4 KB
    __shared__ float buf[64][SW];      // 17.4 KB (p values)

    int t = threadIdx.x, lane = t & 63;
    int w = __builtin_amdgcn_readfirstlane(t >> 6);

    // stage azi tile: linear b128 copy
    {
        const float4* srcp = (const float4*)(azi_ws + ((size_t)bh * NN + i0) * SW);
        float4* dst = (float4*)azis;
        #pragma unroll
        for (int k = 0; k < 5; ++k) {
            int idx = t + 256 * k;
            if (idx < 64 * SW / 4) dst[idx] = srcp[idx];
        }
    }

    // azj row for this lane -> regs (one-time, L1-amortized across waves)
    float4 azj[17];
    {
        const float4* src4 = (const float4*)(azj_ws + ((size_t)bh * NN + j0 + lane) * SW);
        #pragma unroll
        for (int k = 0; k < 17; ++k) azj[k] = src4[k];
    }
    float adjv = adj_ws[bh * NN + j0 + lane];
    float sgn[17];
    {
        const float* sg = sgn_ws + hh * 17;
        #pragma unroll
        for (int k = 0; k < 17; ++k) sgn[k] = sg[k];
    }
    const float* adib = adi_ws + bh * NN + i0;

    __syncthreads();

    // ---- pass A + fused per-i wave softmax partial ----
    float pmk = 0.f, psk = 0.f;
    #pragma unroll 2
    for (int ii = 0; ii < 16; ++ii) {
        int i = 16 * w + ii;
        const float4* arow = (const float4*)(azis + i * SW);
        float acc0 = 0.f, acc1 = 0.f;
        #pragma unroll
        for (int k = 0; k < 17; ++k) {
            float4 zi4 = arow[k];               // ds_read_b128 broadcast
            float s = sgn[k];
            acc0 = fmaf(s, __builtin_fabsf(zi4.x + azj[k].x), acc0);
            acc1 = fmaf(s, __builtin_fabsf(zi4.y + azj[k].y), acc1);
            acc0 = fmaf(s, __builtin_fabsf(zi4.z + azj[k].z), acc0);
            acc1 = fmaf(s, __builtin_fabsf(zi4.w + azj[k].w), acc1);
        }
        float e = adib[i] + adjv + acc0 + acc1;
        float m = e;
        #pragma unroll
        for (int off = 32; off; off >>= 1) m = fmaxf(m, __shfl_xor(m, off));
        float p = __expf(e - m);
        float ssum = p;
        #pragma unroll
        for (int off = 32; off; off >>= 1) ssum += __shfl_xor(ssum, off);
        buf[i][lane] = p;                       // own-wave rows only
        pmk = (lane == ii) ? m : pmk;
        psk = (lane == ii) ? ssum : psk;
    }

    // ---- PV: lane = d, h column in regs, p rows broadcast ----
    float hreg[64];
    {
        const float* hb = h_ws + ((size_t)bh * NN + j0) * DD + lane;
        #pragma unroll
        for (int j = 0; j < 64; ++j) hreg[j] = hb[j * DD];   // coalesced
    }

    size_t obase = ((size_t)(js * 8 + bh) * NN + i0) * DD + lane;
    #pragma unroll 2
    for (int ii = 0; ii < 16; ++ii) {
        int i = 16 * w + ii;
        const float4* prow = (const float4*)buf[i];          // own-wave rows
        float a0 = 0.f, a1 = 0.f;
        #pragma unroll
        for (int k = 0; k < 16; ++k) {
            float4 p4 = prow[k];
            a0 = fmaf(p4.x, hreg[4 * k + 0], a0);
            a1 = fmaf(p4.y, hreg[4 * k + 1], a1);
            a0 = fmaf(p4.z, hreg[4 * k + 2], a0);
            a1 = fmaf(p4.w, hreg[4 * k + 3], a1);
        }
        pacc[obase + (size_t)i * DD] = a0 + a1;
    }
    if (lane < 16) {
        int r = (js * 8 + bh) * NN + i0 + 16 * w + lane;
        pm[r] = pmk; ps[r] = psk;
    }
}

// ---------------------------------------------------------------------------
// combine 8 j-splits + bias. grid = 1024 x 256.
// ---------------------------------------------------------------------------
__global__ __launch_bounds__(256) void combine_kernel(
    const float* __restrict__ pacc, const float* __restrict__ pm,
    const float* __restrict__ ps, const float* __restrict__ bias_param,
    float* __restrict__ out)
{
    int tid = blockIdx.x * 256 + threadIdx.x;
    int d = tid & 63;
    int row = tid >> 6;                 // bh*512 + n, 4096 rows
    int bh = row >> 9, n = row & 511;
    int b = bh >> 2, hh = bh & 3;
    float mv[8];
    float m = -1e30f;
    #pragma unroll
    for (int p = 0; p < 8; ++p) { mv[p] = pm[p * 4096 + row]; m = fmaxf(m, mv[p]); }
    float denom = 0.f, acc = 0.f;
    #pragma unroll
    for (int p = 0; p < 8; ++p) {
        float wgt = __expf(mv[p] - m);
        denom = fmaf(ps[p * 4096 + row], wgt, denom);
        acc = fmaf(pacc[(size_t)p * 262144 + (size_t)row * 64 + d], wgt, acc);
    }
    out[((size_t)b * NN + n) * (HH * DD) + hh * DD + d] =
        acc / denom + bias_param[hh * DD + d];
}

extern "C" void kernel_launch(void* const* d_in, const int* in_sizes, int n_in,
                              void* d_out, int out_size, void* d_ws, size_t ws_size,
                              hipStream_t stream) {
    const float* x    = (const float*)d_in[0];
    const float* Wp   = (const float*)d_in[1];
    const float* bp   = (const float*)d_in[2];
    const float* Wc   = (const float*)d_in[3];
    const float* Wcb  = (const float*)d_in[4];
    const float* a    = (const float*)d_in[5];
    const float* bpar = (const float*)d_in[6];
    float* out = (float*)d_out;

    float* ws     = (float*)d_ws;
    float* h_ws   = ws;
    float* azi_ws = ws + 262144;
    float* azj_ws = ws + 540672;
    float* adi_ws = ws + 819200;
    float* adj_ws = ws + 823296;
    float* pacc   = ws + 827392;
    float* pm     = ws + 2924544;
    float* ps     = ws + 2957312;
    float* sgn_ws = ws + 2990080;
    float* pa_ws  = ws + 2990148;
    int*   src_ws = (int*)(ws + 2990420);

    prep_kernel<<<dim3(1), dim3(64), 0, stream>>>(a, sgn_ws, pa_ws, src_ws);
    proj_kernel<<<dim3(512), dim3(256), 0, stream>>>(
        x, Wp, bp, Wc, Wcb, a, pa_ws, src_ws,
        h_ws, azi_ws, azj_ws, adi_ws, adj_ws);
    attn_kernel<<<dim3(512), dim3(256), 0, stream>>>(
        h_ws, azi_ws, azj_ws, adi_ws, adj_ws, sgn_ws, pacc, pm, ps);
    combine_kernel<<<dim3(1024), dim3(256), 0, stream>>>(
        pacc, pm, ps, bpar, out);
}

// Round 5
// 44.747 us; speedup vs baseline: 1.1214x; 1.1214x over previous
//
#include <hip/hip_runtime.h>
#include <hip/hip_bf16.h>

#define NN 512
#define FIN 128
#define HH 4
#define DD 64
#define SW 68   // permuted/padded e-width: 17 groups x 4

// ws layout (floats):
//  h_ws   [8][512][64]        262144  @ 0
//  azi_ws [8][512][68]        278528  @ 262144   (|a|-scaled, e-permuted, zi+Wcb)
//  azj_ws [8][512][68]        278528  @ 540672
//  adi_ws [8][512]            4096    @ 819200   (0.6 * sum_e a*zi')
//  adj_ws [8][512]            4096    @ 823296
//  pacc   [8][8][512][64]     2097152 @ 827392
//  pm     [8][4096]           32768   @ 2924544
//  ps     [8][4096]           32768   @ 2957312

// ---------------------------------------------------------------------------
// proj: h = x@Wp + bp ; zi' = h@W1^T + Wcb ; zj = h@W2^T ; adi/adj dots ;
// inline sign-partition scatter of |a|-scaled azi/azj. 512 blocks x 256.
// ---------------------------------------------------------------------------
__global__ __launch_bounds__(256) void proj_kernel(
    const float* __restrict__ x, const float* __restrict__ Wp,
    const float* __restrict__ bp, const float* __restrict__ Wc,
    const float* __restrict__ Wcb, const float* __restrict__ a,
    float* __restrict__ h_ws, float* __restrict__ azi_ws, float* __restrict__ azj_ws,
    float* __restrict__ adi_ws, float* __restrict__ adj_ws)
{
    int blk = blockIdx.x;
    int bh = blk >> 6;
    int n0 = (blk & 63) << 3;
    int b = bh >> 2, hh = bh & 3;

    __shared__ float xs[8 * FIN];          // 4 KB
    __shared__ float hs[8][DD];            // 2 KB
    __shared__ float Wcs[DD][2 * DD + 1];  // 33 KB

    int t = threadIdx.x;

    ((float4*)xs)[t] = ((const float4*)(x + ((size_t)b * NN + n0) * FIN))[t];
    {
        const float4* wg = (const float4*)(Wc + (size_t)hh * DD * 2 * DD);
        #pragma unroll
        for (int k = 0; k < 8; ++k) {
            int idx = t + 256 * k;
            int r = idx >> 5, c4 = (idx & 31) * 4;
            float4 v = wg[idx];
            Wcs[r][c4] = v.x; Wcs[r][c4 + 1] = v.y;
            Wcs[r][c4 + 2] = v.z; Wcs[r][c4 + 3] = v.w;
        }
    }
    __syncthreads();

    int e = t & 63, w = t >> 6;            // rows w, w+4
    const float* Wph = Wp + (size_t)hh * FIN * DD;
    float bpv = bp[hh * DD + e];
    float acc0 = bpv, acc1 = bpv;
    #pragma unroll 8
    for (int i = 0; i < FIN; ++i) {
        float wv = Wph[i * DD + e];
        acc0 = fmaf(xs[w * FIN + i], wv, acc0);
        acc1 = fmaf(xs[(w + 4) * FIN + i], wv, acc1);
    }
    hs[w][e] = acc0; hs[w + 4][e] = acc1;
    float* hg = h_ws + ((size_t)bh * NN + n0) * DD;
    hg[w * DD + e] = acc0; hg[(w + 4) * DD + e] = acc1;
    __syncthreads();

    float zb = Wcb[hh * DD + e];
    float zi0 = zb, zi1 = zb, zj0 = 0.f, zj1 = 0.f;
    #pragma unroll 8
    for (int d2 = 0; d2 < DD; ++d2) {
        float w1 = Wcs[e][d2];
        float w2 = Wcs[e][DD + d2];
        float h0 = hs[w][d2], h1 = hs[w + 4][d2];   // broadcast
        zi0 = fmaf(h0, w1, zi0); zi1 = fmaf(h1, w1, zi1);
        zj0 = fmaf(h0, w2, zj0); zj1 = fmaf(h1, w2, zj1);
    }

    // adi = 0.6*sum_e a*zi' ; adj = 0.6*sum_e a*zj
    float av = a[hh * DD + e];
    float p0 = av * zi0, p1 = av * zi1, q0 = av * zj0, q1 = av * zj1;
    #pragma unroll
    for (int off = 32; off; off >>= 1) {
        p0 += __shfl_xor(p0, off); p1 += __shfl_xor(p1, off);
        q0 += __shfl_xor(q0, off); q1 += __shfl_xor(q1, off);
    }
    if (e == 0) {
        adi_ws[bh * NN + n0 + w]     = 0.6f * p0;
        adi_ws[bh * NN + n0 + w + 4] = 0.6f * p1;
        adj_ws[bh * NN + n0 + w]     = 0.6f * q0;
        adj_ws[bh * NN + n0 + w + 4] = 0.6f * q1;
    }

    // sign-partition permutation (wave ballot; lane = e), scatter from regs
    unsigned long long mask = __ballot(av >= 0.f);
    int np = __popcll(mask);
    int GP = (np + 3) >> 2;
    int below = __popcll(mask & ((1ull << e) - 1ull));
    int slot = (av >= 0.f) ? below : (4 * GP + (e - below));
    float pav = __builtin_fabsf(av);

    float* azib = azi_ws + ((size_t)bh * NN + n0) * SW;
    float* azjb = azj_ws + ((size_t)bh * NN + n0) * SW;
    azib[w * SW + slot]       = pav * zi0;
    azib[(w + 4) * SW + slot] = pav * zi1;
    azjb[w * SW + slot]       = pav * zj0;
    azjb[(w + 4) * SW + slot] = pav * zj1;
    // 4 pad slots per row -> zero
    int p1c = 4 * GP - np;
    if (e < 4) {
        int psl = (e < p1c) ? (np + e) : (4 * GP + 64 - np + (e - p1c));
        azib[w * SW + psl] = 0.f; azib[(w + 4) * SW + psl] = 0.f;
        azjb[w * SW + psl] = 0.f; azjb[(w + 4) * SW + psl] = 0.f;
    }
}

// ---------------------------------------------------------------------------
// attn partial: tile [8 i][64 j], grid = 8bh x 64it x 8js = 4096 blocks x 256.
// wave w owns i = 2w, 2w+1; lane = j (pass A) then lane = d (PV). ONE barrier.
// ---------------------------------------------------------------------------
__global__ __launch_bounds__(256) void attn_kernel(
    const float* __restrict__ h_ws, const float* __restrict__ azi_ws,
    const float* __restrict__ azj_ws, const float* __restrict__ adi_ws,
    const float* __restrict__ adj_ws, const float* __restrict__ a,
    float* __restrict__ pacc, float* __restrict__ pm, float* __restrict__ ps)
{
    int blk = blockIdx.x;
    int js = blk & 7, it = (blk >> 3) & 63, bh = blk >> 9;
    int j0 = js << 6, i0 = it << 3, hh = bh & 3;

    __shared__ float azis[8 * SW];     // 2.2 KB
    __shared__ float pbuf[8][64];      // 2 KB (wave-private rows)
    __shared__ float htile[64 * 64];   // 16 KB

    int t = threadIdx.x, lane = t & 63;
    int w = t >> 6;

    // stage azi rows + h tile (coalesced b128)
    if (t < 136)
        ((float4*)azis)[t] = ((const float4*)(azi_ws + ((size_t)bh * NN + i0) * SW))[t];
    {
        const float4* hsrc = (const float4*)(h_ws + ((size_t)bh * NN + j0) * DD);
        float4* hdst = (float4*)htile;
        #pragma unroll
        for (int k = 0; k < 4; ++k) hdst[t + 256 * k] = hsrc[t + 256 * k];
    }

    // per-lane azj row in regs
    float4 azj[17];
    {
        const float4* srcj = (const float4*)(azj_ws + ((size_t)bh * NN + j0 + lane) * SW);
        #pragma unroll
        for (int k = 0; k < 17; ++k) azj[k] = srcj[k];
    }
    float adjv = adj_ws[bh * NN + j0 + lane];

    // group signs from ballot of a (lane = e)
    float av_e = a[hh * DD + lane];
    unsigned long long mask = __ballot(av_e >= 0.f);
    int GP = (__popcll(mask) + 3) >> 2;
    float sgn[17];
    #pragma unroll
    for (int k = 0; k < 17; ++k) sgn[k] = (k < GP) ? 0.4f : -0.4f;

    float adiA = adi_ws[bh * NN + i0 + 2 * w];
    float adiB = adi_ws[bh * NN + i0 + 2 * w + 1];

    __syncthreads();

    // ---- pass A + full softmax partial for rows 2w, 2w+1 ----
    #pragma unroll
    for (int ii = 0; ii < 2; ++ii) {
        int i = 2 * w + ii;
        const float4* arow = (const float4*)(azis + i * SW);
        float acc0 = 0.f, acc1 = 0.f;
        #pragma unroll
        for (int k = 0; k < 17; ++k) {
            float4 zi4 = arow[k];               // uniform b128 broadcast
            float s = sgn[k];
            acc0 = fmaf(s, __builtin_fabsf(zi4.x + azj[k].x), acc0);
            acc1 = fmaf(s, __builtin_fabsf(zi4.y + azj[k].y), acc1);
            acc0 = fmaf(s, __builtin_fabsf(zi4.z + azj[k].z), acc0);
            acc1 = fmaf(s, __builtin_fabsf(zi4.w + azj[k].w), acc1);
        }
        float ev = ((ii == 0) ? adiA : adiB) + adjv + acc0 + acc1;
        float m = ev;
        #pragma unroll
        for (int off = 32; off; off >>= 1) m = fmaxf(m, __shfl_xor(m, off));
        float p = __expf(ev - m);
        float ssum = p;
        #pragma unroll
        for (int off = 32; off; off >>= 1) ssum += __shfl_xor(ssum, off);
        pbuf[i][lane] = p;
        if (lane == 0) {
            pm[(js * 8 + bh) * NN + i0 + i] = m;
            ps[(js * 8 + bh) * NN + i0 + i] = ssum;
        }
    }

    // ---- PV: lane = d; own-wave pbuf rows (no barrier needed) ----
    float accA = 0.f, accB = 0.f;
    const float4* pA = (const float4*)pbuf[2 * w];
    const float4* pB = (const float4*)pbuf[2 * w + 1];
    #pragma unroll
    for (int k = 0; k < 16; ++k) {
        float4 a4 = pA[k], b4 = pB[k];
        float h0 = htile[(4 * k + 0) * 64 + lane];
        float h1 = htile[(4 * k + 1) * 64 + lane];
        float h2 = htile[(4 * k + 2) * 64 + lane];
        float h3 = htile[(4 * k + 3) * 64 + lane];
        accA = fmaf(a4.x, h0, accA); accB = fmaf(b4.x, h0, accB);
        accA = fmaf(a4.y, h1, accA); accB = fmaf(b4.y, h1, accB);
        accA = fmaf(a4.z, h2, accA); accB = fmaf(b4.z, h2, accB);
        accA = fmaf(a4.w, h3, accA); accB = fmaf(b4.w, h3, accB);
    }
    size_t ob = ((size_t)(js * 8 + bh) * NN + i0 + 2 * w) * DD + lane;
    pacc[ob] = accA;
    pacc[ob + DD] = accB;
}

// ---------------------------------------------------------------------------
// combine 8 j-splits + bias. grid = 1024 x 256.
// ---------------------------------------------------------------------------
__global__ __launch_bounds__(256) void combine_kernel(
    const float* __restrict__ pacc, const float* __restrict__ pm,
    const float* __restrict__ ps, const float* __restrict__ bias_param,
    float* __restrict__ out)
{
    int tid = blockIdx.x * 256 + threadIdx.x;
    int d = tid & 63;
    int row = tid >> 6;                 // bh*512 + n, 4096 rows
    int bh = row >> 9, n = row & 511;
    int b = bh >> 2, hh = bh & 3;
    float mv[8];
    float m = -1e30f;
    #pragma unroll
    for (int p = 0; p < 8; ++p) { mv[p] = pm[p * 4096 + row]; m = fmaxf(m, mv[p]); }
    float denom = 0.f, acc = 0.f;
    #pragma unroll
    for (int p = 0; p < 8; ++p) {
        float wgt = __expf(mv[p] - m);
        denom = fmaf(ps[p * 4096 + row], wgt, denom);
        acc = fmaf(pacc[(size_t)p * 262144 + (size_t)row * 64 + d], wgt, acc);
    }
    out[((size_t)b * NN + n) * (HH * DD) + hh * DD + d] =
        acc / denom + bias_param[hh * DD + d];
}

extern "C" void kernel_launch(void* const* d_in, const int* in_sizes, int n_in,
                              void* d_out, int out_size, void* d_ws, size_t ws_size,
                              hipStream_t stream) {
    const float* x    = (const float*)d_in[0];
    const float* Wp   = (const float*)d_in[1];
    const float* bp   = (const float*)d_in[2];
    const float* Wc   = (const float*)d_in[3];
    const float* Wcb  = (const float*)d_in[4];
    const float* a    = (const float*)d_in[5];
    const float* bpar = (const float*)d_in[6];
    float* out = (float*)d_out;

    float* ws     = (float*)d_ws;
    float* h_ws   = ws;
    float* azi_ws = ws + 262144;
    float* azj_ws = ws + 540672;
    float* adi_ws = ws + 819200;
    float* adj_ws = ws + 823296;
    float* pacc   = ws + 827392;
    float* pm     = ws + 2924544;
    float* ps     = ws + 2957312;

    proj_kernel<<<dim3(512), dim3(256), 0, stream>>>(
        x, Wp, bp, Wc, Wcb, a, h_ws, azi_ws, azj_ws, adi_ws, adj_ws);
    attn_kernel<<<dim3(4096), dim3(256), 0, stream>>>(
        h_ws, azi_ws, azj_ws, adi_ws, adj_ws, a, pacc, pm, ps);
    combine_kernel<<<dim3(1024), dim3(256), 0, stream>>>(
        pacc, pm, ps, bpar, out);
}

// Round 6
// 44.673 us; speedup vs baseline: 1.1232x; 1.0016x over previous
//
#include <hip/hip_runtime.h>
#include <hip/hip_bf16.h>

#define NN 512
#define FIN 128
#define HH 4
#define DD 64
#define SW 68   // permuted/padded e-width: 17 groups x 4

// ws layout (floats):
//  h_ws   [8][512][64]        262144  @ 0
//  azi_ws [8][512][68]        278528  @ 262144   (|a|-scaled, e-permuted, zi+Wcb)
//  azjT   [8][68][512]        278528  @ 540672   (transposed: slot-major, j fastest)
//  adi_ws [8][512]            4096    @ 819200   (0.6 * sum_e a*zi')
//  adj_ws [8][512]            4096    @ 823296
//  pacc   [8][8][512][64]     2097152 @ 827392
//  pm     [8][4096]           32768   @ 2924544
//  ps     [8][4096]           32768   @ 2957312

// ---------------------------------------------------------------------------
// proj: h = x@Wp + bp ; zi' = h@W1^T + Wcb ; zj = h@W2^T ; adi/adj dots ;
// sign-partition scatter of azi (row-major) and azjT (transposed).
// 512 blocks x 256.
// ---------------------------------------------------------------------------
__global__ __launch_bounds__(256) void proj_kernel(
    const float* __restrict__ x, const float* __restrict__ Wp,
    const float* __restrict__ bp, const float* __restrict__ Wc,
    const float* __restrict__ Wcb, const float* __restrict__ a,
    float* __restrict__ h_ws, float* __restrict__ azi_ws, float* __restrict__ azjT,
    float* __restrict__ adi_ws, float* __restrict__ adj_ws)
{
    int blk = blockIdx.x;
    int bh = blk >> 6;
    int n0 = (blk & 63) << 3;
    int b = bh >> 2, hh = bh & 3;

    __shared__ float xs[8 * FIN];          // 4 KB
    __shared__ float hs[8][DD];            // 2 KB
    __shared__ float Wcs[DD][2 * DD + 1];  // 33 KB
    __shared__ float tzj[8][DD + 1];       // 2 KB (pad 65: column reads spread banks)
    __shared__ int   slot2e[SW];
    __shared__ float slot2pa[SW];

    int t = threadIdx.x;

    ((float4*)xs)[t] = ((const float4*)(x + ((size_t)b * NN + n0) * FIN))[t];
    {
        const float4* wg = (const float4*)(Wc + (size_t)hh * DD * 2 * DD);
        #pragma unroll
        for (int k = 0; k < 8; ++k) {
            int idx = t + 256 * k;
            int r = idx >> 5, c4 = (idx & 31) * 4;
            float4 v = wg[idx];
            Wcs[r][c4] = v.x; Wcs[r][c4 + 1] = v.y;
            Wcs[r][c4 + 2] = v.z; Wcs[r][c4 + 3] = v.w;
        }
    }
    __syncthreads();

    int e = t & 63, w = t >> 6;            // rows w, w+4
    const float* Wph = Wp + (size_t)hh * FIN * DD;
    float bpv = bp[hh * DD + e];
    float acc0 = bpv, acc1 = bpv;
    #pragma unroll 8
    for (int i = 0; i < FIN; ++i) {
        float wv = Wph[i * DD + e];
        acc0 = fmaf(xs[w * FIN + i], wv, acc0);
        acc1 = fmaf(xs[(w + 4) * FIN + i], wv, acc1);
    }
    hs[w][e] = acc0; hs[w + 4][e] = acc1;
    float* hg = h_ws + ((size_t)bh * NN + n0) * DD;
    hg[w * DD + e] = acc0; hg[(w + 4) * DD + e] = acc1;
    __syncthreads();

    float zb = Wcb[hh * DD + e];
    float zi0 = zb, zi1 = zb, zj0 = 0.f, zj1 = 0.f;
    #pragma unroll 8
    for (int d2 = 0; d2 < DD; ++d2) {
        float w1 = Wcs[e][d2];
        float w2 = Wcs[e][DD + d2];
        float h0 = hs[w][d2], h1 = hs[w + 4][d2];   // broadcast
        zi0 = fmaf(h0, w1, zi0); zi1 = fmaf(h1, w1, zi1);
        zj0 = fmaf(h0, w2, zj0); zj1 = fmaf(h1, w2, zj1);
    }
    tzj[w][e] = zj0; tzj[w + 4][e] = zj1;

    // adi = 0.6*sum_e a*zi' ; adj = 0.6*sum_e a*zj
    float av = a[hh * DD + e];
    float p0 = av * zi0, p1 = av * zi1, q0 = av * zj0, q1 = av * zj1;
    #pragma unroll
    for (int off = 32; off; off >>= 1) {
        p0 += __shfl_xor(p0, off); p1 += __shfl_xor(p1, off);
        q0 += __shfl_xor(q0, off); q1 += __shfl_xor(q1, off);
    }
    if (e == 0) {
        adi_ws[bh * NN + n0 + w]     = 0.6f * p0;
        adi_ws[bh * NN + n0 + w + 4] = 0.6f * p1;
        adj_ws[bh * NN + n0 + w]     = 0.6f * q0;
        adj_ws[bh * NN + n0 + w + 4] = 0.6f * q1;
    }

    // sign-partition permutation (wave ballot; lane = e)
    unsigned long long mask = __ballot(av >= 0.f);
    int np = __popcll(mask);
    int GP = (np + 3) >> 2;
    int below = __popcll(mask & ((1ull << e) - 1ull));
    int slot = (av >= 0.f) ? below : (4 * GP + (e - below));
    float pav = __builtin_fabsf(av);

    // azi: row-major scatter (within-row: 5 cache lines, cheap)
    float* azib = azi_ws + ((size_t)bh * NN + n0) * SW;
    azib[w * SW + slot]       = pav * zi0;
    azib[(w + 4) * SW + slot] = pav * zi1;
    if (w == 0) { slot2e[slot] = e; slot2pa[slot] = pav; }
    int p1c = 4 * GP - np;
    if (e < 4) {
        int psl = (e < p1c) ? (np + e) : (4 * GP + 64 - np + (e - p1c));
        azib[w * SW + psl] = 0.f; azib[(w + 4) * SW + psl] = 0.f;
        if (w == 0) { slot2e[psl] = 0; slot2pa[psl] = 0.f; }
    }
    __syncthreads();

    // azjT transposed write: [bh][slot][n], 8 consecutive n per slot (32B segs)
    for (int idx = t; idx < SW * 8; idx += 256) {
        int slot = idx >> 3, r = idx & 7;
        float v = slot2pa[slot] * tzj[r][slot2e[slot]];
        azjT[((size_t)bh * SW + slot) * NN + n0 + r] = v;
    }
}

// ---------------------------------------------------------------------------
// attn partial: tile [8 i][64 j], grid = 8bh x 64it x 8js = 4096 blocks x 256.
// wave w owns i = 2w, 2w+1; lane = j (pass A) then lane = d (PV). ONE barrier.
// All global operand loads coalesced.
// ---------------------------------------------------------------------------
__global__ __launch_bounds__(256) void attn_kernel(
    const float* __restrict__ h_ws, const float* __restrict__ azi_ws,
    const float* __restrict__ azjT, const float* __restrict__ adi_ws,
    const float* __restrict__ adj_ws, const float* __restrict__ a,
    float* __restrict__ pacc, float* __restrict__ pm, float* __restrict__ ps)
{
    int blk = blockIdx.x;
    int js = blk & 7, it = (blk >> 3) & 63, bh = blk >> 9;
    int j0 = js << 6, i0 = it << 3, hh = bh & 3;

    __shared__ float azis[8 * SW];     // 2.2 KB
    __shared__ float pbuf[8][64];      // 2 KB (wave-private rows)
    __shared__ float htile[64 * 64];   // 16 KB

    int t = threadIdx.x, lane = t & 63;
    int w = t >> 6;

    // stage azi rows + h tile (coalesced b128)
    if (t < 136)
        ((float4*)azis)[t] = ((const float4*)(azi_ws + ((size_t)bh * NN + i0) * SW))[t];
    {
        const float4* hsrc = (const float4*)(h_ws + ((size_t)bh * NN + j0) * DD);
        float4* hdst = (float4*)htile;
        #pragma unroll
        for (int k = 0; k < 4; ++k) hdst[t + 256 * k] = hsrc[t + 256 * k];
    }

    // per-lane azj column from transposed ws: 68 coalesced dword loads
    float azjr[SW];
    {
        const float* ajT = azjT + (size_t)bh * SW * NN + j0 + lane;
        #pragma unroll
        for (int k = 0; k < SW; ++k) azjr[k] = ajT[(size_t)k * NN];
    }
    float adjv = adj_ws[bh * NN + j0 + lane];

    // group signs from ballot of a (lane = e)
    float av_e = a[hh * DD + lane];
    unsigned long long mask = __ballot(av_e >= 0.f);
    int GP = (__popcll(mask) + 3) >> 2;
    float sgn[17];
    #pragma unroll
    for (int k = 0; k < 17; ++k) sgn[k] = (k < GP) ? 0.4f : -0.4f;

    float adiA = adi_ws[bh * NN + i0 + 2 * w];
    float adiB = adi_ws[bh * NN + i0 + 2 * w + 1];

    __syncthreads();

    // ---- pass A + full softmax partial for rows 2w, 2w+1 ----
    #pragma unroll
    for (int ii = 0; ii < 2; ++ii) {
        int i = 2 * w + ii;
        const float4* arow = (const float4*)(azis + i * SW);
        float acc0 = 0.f, acc1 = 0.f;
        #pragma unroll
        for (int k = 0; k < 17; ++k) {
            float4 zi4 = arow[k];               // uniform b128 broadcast
            float s = sgn[k];
            acc0 = fmaf(s, __builtin_fabsf(zi4.x + azjr[4 * k + 0]), acc0);
            acc1 = fmaf(s, __builtin_fabsf(zi4.y + azjr[4 * k + 1]), acc1);
            acc0 = fmaf(s, __builtin_fabsf(zi4.z + azjr[4 * k + 2]), acc0);
            acc1 = fmaf(s, __builtin_fabsf(zi4.w + azjr[4 * k + 3]), acc1);
        }
        float ev = ((ii == 0) ? adiA : adiB) + adjv + acc0 + acc1;
        float m = ev;
        #pragma unroll
        for (int off = 32; off; off >>= 1) m = fmaxf(m, __shfl_xor(m, off));
        float p = __expf(ev - m);
        float ssum = p;
        #pragma unroll
        for (int off = 32; off; off >>= 1) ssum += __shfl_xor(ssum, off);
        pbuf[i][lane] = p;
        if (lane == 0) {
            pm[(js * 8 + bh) * NN + i0 + i] = m;
            ps[(js * 8 + bh) * NN + i0 + i] = ssum;
        }
    }

    // ---- PV: lane = d; own-wave pbuf rows (no barrier needed) ----
    float accA = 0.f, accB = 0.f;
    const float4* pA = (const float4*)pbuf[2 * w];
    const float4* pB = (const float4*)pbuf[2 * w + 1];
    #pragma unroll
    for (int k = 0; k < 16; ++k) {
        float4 a4 = pA[k], b4 = pB[k];
        float h0 = htile[(4 * k + 0) * 64 + lane];
        float h1 = htile[(4 * k + 1) * 64 + lane];
        float h2 = htile[(4 * k + 2) * 64 + lane];
        float h3 = htile[(4 * k + 3) * 64 + lane];
        accA = fmaf(a4.x, h0, accA); accB = fmaf(b4.x, h0, accB);
        accA = fmaf(a4.y, h1, accA); accB = fmaf(b4.y, h1, accB);
        accA = fmaf(a4.z, h2, accA); accB = fmaf(b4.z, h2, accB);
        accA = fmaf(a4.w, h3, accA); accB = fmaf(b4.w, h3, accB);
    }
    size_t ob = ((size_t)(js * 8 + bh) * NN + i0 + 2 * w) * DD + lane;
    pacc[ob] = accA;
    pacc[ob + DD] = accB;
}

// ---------------------------------------------------------------------------
// combine 8 j-splits + bias. grid = 1024 x 256.
// ---------------------------------------------------------------------------
__global__ __launch_bounds__(256) void combine_kernel(
    const float* __restrict__ pacc, const float* __restrict__ pm,
    const float* __restrict__ ps, const float* __restrict__ bias_param,
    float* __restrict__ out)
{
    int tid = blockIdx.x * 256 + threadIdx.x;
    int d = tid & 63;
    int row = tid >> 6;                 // bh*512 + n, 4096 rows
    int bh = row >> 9, n = row & 511;
    int b = bh >> 2, hh = bh & 3;
    float mv[8];
    float m = -1e30f;
    #pragma unroll
    for (int p = 0; p < 8; ++p) { mv[p] = pm[p * 4096 + row]; m = fmaxf(m, mv[p]); }
    float denom = 0.f, acc = 0.f;
    #pragma unroll
    for (int p = 0; p < 8; ++p) {
        float wgt = __expf(mv[p] - m);
        denom = fmaf(ps[p * 4096 + row], wgt, denom);
        acc = fmaf(pacc[(size_t)p * 262144 + (size_t)row * 64 + d], wgt, acc);
    }
    out[((size_t)b * NN + n) * (HH * DD) + hh * DD + d] =
        acc / denom + bias_param[hh * DD + d];
}

extern "C" void kernel_launch(void* const* d_in, const int* in_sizes, int n_in,
                              void* d_out, int out_size, void* d_ws, size_t ws_size,
                              hipStream_t stream) {
    const float* x    = (const float*)d_in[0];
    const float* Wp   = (const float*)d_in[1];
    const float* bp   = (const float*)d_in[2];
    const float* Wc   = (const float*)d_in[3];
    const float* Wcb  = (const float*)d_in[4];
    const float* a    = (const float*)d_in[5];
    const float* bpar = (const float*)d_in[6];
    float* out = (float*)d_out;

    float* ws     = (float*)d_ws;
    float* h_ws   = ws;
    float* azi_ws = ws + 262144;
    float* azjT   = ws + 540672;
    float* adi_ws = ws + 819200;
    float* adj_ws = ws + 823296;
    float* pacc   = ws + 827392;
    float* pm     = ws + 2924544;
    float* ps     = ws + 2957312;

    proj_kernel<<<dim3(512), dim3(256), 0, stream>>>(
        x, Wp, bp, Wc, Wcb, a, h_ws, azi_ws, azjT, adi_ws, adj_ws);
    attn_kernel<<<dim3(4096), dim3(256), 0, stream>>>(
        h_ws, azi_ws, azjT, adi_ws, adj_ws, a, pacc, pm, ps);
    combine_kernel<<<dim3(1024), dim3(256), 0, stream>>>(
        pacc, pm, ps, bpar, out);
}